// Round 11
// baseline (189.527 us; speedup 1.0000x reference)
//
#include <hip/hip_runtime.h>
#include <math.h>

// Problem constants
#define B_  64
#define T_  256
#define IN_ 512
#define HID_ 1024
#define OUT_ 256
#define NDOM 20

typedef __bf16 bf16_t;
typedef __bf16 bf16x8 __attribute__((ext_vector_type(8)));
typedef float  f32x4  __attribute__((ext_vector_type(4)));

// fp32 -> bf16 RNE, pure bit math
__device__ __forceinline__ unsigned f2bf_bits(float f) {
    unsigned u = __builtin_bit_cast(unsigned, f);
    return (u + 0x7FFFu + ((u >> 16) & 1u)) >> 16;
}
__device__ __forceinline__ unsigned pack_bf16x2(float x, float y) {
    return f2bf_bits(x) | (f2bf_bits(y) << 16);
}

// Async global->LDS, 16 B per lane. LDS dest = wave-uniform base + lane*16 (m104).
__device__ __forceinline__ void gl_lds16(const void* g, void* l) {
    __builtin_amdgcn_global_load_lds(
        (const __attribute__((address_space(1))) unsigned*)g,
        (__attribute__((address_space(3))) unsigned*)l,
        16, 0, 0);
}

// ---------------------------------------------------------------------------
// Fused prepass (one dispatch, 12032 blocks):
//   blocks [0,8192):      X fp32 -> Xbf bf16 (dense, 256 float4/block)
//   blocks [8192,10752):  W1 (512x1024) -> W1t bf16 [n][k] + b1  (128 tiles/dom)
//   blocks [10752,12032): W2 (1024x256) -> W2t bf16 [n][k] + b2  (64 tiles/dom)
__global__ __launch_bounds__(256) void prepass(
    const float* __restrict__ X,  bf16_t* __restrict__ Xbf,
    const float* __restrict__ t1, bf16_t* __restrict__ W1t, float* __restrict__ b1,
    const float* __restrict__ t2, bf16_t* __restrict__ W2t, float* __restrict__ b2)
{
    const int bid = blockIdx.x;
    const int tid = threadIdx.x;

    if (bid < 8192) {
        const size_t idx = (size_t)bid * 256 + tid;
        float4 v = ((const float4*)X)[idx];
        uint2 p;
        p.x = pack_bf16x2(v.x, v.y);
        p.y = pack_bf16x2(v.z, v.w);
        ((uint2*)Xbf)[idx] = p;
        return;
    }

    __shared__ float t[64][65];

    const float* table; bf16_t* Wt; float* Bias;
    int K, N, d, n0, k0;
    if (bid < 10752) {
        const int r = bid - 8192;             // 2560 = 20 dom x 128 tiles
        K = IN_; N = HID_;
        d = r >> 7;
        n0 = (r & 15) * 64;                   // 16 n-tiles
        k0 = ((r >> 4) & 7) * 64;             // 8 k-tiles
        table = t1; Wt = W1t; Bias = b1;
    } else {
        const int r = bid - 10752;            // 1280 = 20 dom x 64 tiles
        K = HID_; N = OUT_;
        d = r >> 6;
        n0 = (r & 3) * 64;                    // 4 n-tiles
        k0 = ((r >> 2) & 15) * 64;            // 16 k-tiles
        table = t2; Wt = W2t; Bias = b2;
    }

    const float* W = table + (size_t)d * ((size_t)K * N + N);

    #pragma unroll
    for (int r = 0; r < 4; ++r) {
        const int kl = (tid >> 4) + r * 16;
        const int nl = (tid & 15) * 4;
        float4 v = *(const float4*)(W + (size_t)(k0 + kl) * N + n0 + nl);
        t[kl][nl + 0] = v.x; t[kl][nl + 1] = v.y;
        t[kl][nl + 2] = v.z; t[kl][nl + 3] = v.w;
    }
    __syncthreads();

    bf16_t* Wtd = Wt + (size_t)d * K * N;
    #pragma unroll
    for (int r = 0; r < 4; ++r) {
        const int nl = (tid >> 4) + r * 16;
        const int k4 = (tid & 15) * 4;
        uint2 p;
        p.x = pack_bf16x2(t[k4 + 0][nl], t[k4 + 1][nl]);
        p.y = pack_bf16x2(t[k4 + 2][nl], t[k4 + 3][nl]);
        *(uint2*)(Wtd + (size_t)(n0 + nl) * K + k0 + k4) = p;
    }

    if (k0 == 0 && tid < 64)
        Bias[(size_t)d * N + n0 + tid] = W[(size_t)K * N + n0 + tid];
}

// ---------------------------------------------------------------------------
// fc1: H[b] = gelu(Xbf[b] (256x512 bf16) @ W1t[d]^T + b1), H bf16.
// 128x128 tile, BK=64, all-bf16 async staging. Swapped-operand MFMA (D^T):
// lane&15 = m, quad*4+reg = 4 consecutive n. Epilogue through LDS for
// fully-coalesced 256 B H-row stores.  [R10-validated: 44 us, MfmaUtil 14%]
#define CT_STRIDE 136   // 128 data + 8 pad = 272 B (16-B mult; >= tile width!)
__global__ __launch_bounds__(256) void fc1_gemm(
    const bf16_t* __restrict__ Xbf,   // B x 256 x 512
    const bf16_t* __restrict__ W1t,   // D x 1024 x 512 [n][k]
    const float*  __restrict__ Bias,  // D x 1024
    const int*    __restrict__ hetero,
    bf16_t*       __restrict__ H)     // B x 256 x 1024
{
    const int id   = blockIdx.x;          // 1024 blocks
    const int g    = id & 127;            // stride-128 ids share X-tile -> same XCD
    const int nidx = id >> 7;
    const int b    = g >> 1;
    const int m0   = (g & 1) * 128;
    const int n0   = nidx * 128;
    const int d    = hetero[2 * b];
    const bf16_t* W    = W1t + (size_t)d * HID_ * IN_;
    const float*  bias = Bias + (size_t)d * HID_;
    const bf16_t* A    = Xbf + (size_t)(b * 256 + m0) * IN_;

    __shared__ __attribute__((aligned(16))) char smem[128 * CT_STRIDE * 2];  // 34816 B
    bf16_t* LdsA = (bf16_t*)smem;             // [128][64] 16 KB
    bf16_t* LdsB = (bf16_t*)(smem + 16384);   // [128][64] 16 KB
    bf16_t* Ct   = (bf16_t*)smem;             // epilogue [128][CT_STRIDE] (aliases)

    const int tid  = threadIdx.x;
    const int wave = tid >> 6;
    const int lane = tid & 63;
    const int l16  = lane & 15;
    const int quad = lane >> 4;
    const int wm   = (wave >> 1) * 64;
    const int wn   = (wave & 1) * 64;

    f32x4 acc[4][4] = {};

    for (int kk = 0; kk < IN_; kk += 64) {
        #pragma unroll
        for (int cc = 0; cc < 4; ++cc) {
            const int r0  = wave * 32 + cc * 8;
            const int row = r0 + (lane >> 3);
            const int cs  = (lane & 7) ^ (row & 7);
            gl_lds16(A + (size_t)row * IN_ + kk + cs * 8, &LdsA[r0 * 64]);
        }
        #pragma unroll
        for (int cc = 0; cc < 4; ++cc) {
            const int r0  = wave * 32 + cc * 8;
            const int row = r0 + (lane >> 3);
            const int cs  = (lane & 7) ^ (row & 7);
            gl_lds16(W + (size_t)(n0 + row) * IN_ + kk + cs * 8, &LdsB[r0 * 64]);
        }
        __syncthreads();

        #pragma unroll
        for (int h = 0; h < 2; ++h) {
            bf16x8 af[4], bfg[4];
            #pragma unroll
            for (int i = 0; i < 4; ++i) {
                const int r = wm + i * 16 + l16;
                const int c = (h * 4 + quad) ^ (r & 7);
                af[i] = *(const bf16x8*)&LdsA[r * 64 + c * 8];
            }
            #pragma unroll
            for (int j = 0; j < 4; ++j) {
                const int r = wn + j * 16 + l16;
                const int c = (h * 4 + quad) ^ (r & 7);
                bfg[j] = *(const bf16x8*)&LdsB[r * 64 + c * 8];
            }
            #pragma unroll
            for (int i = 0; i < 4; ++i)
                #pragma unroll
                for (int j = 0; j < 4; ++j)   // swapped operands -> D^T
                    acc[i][j] = __builtin_amdgcn_mfma_f32_16x16x32_bf16(bfg[j], af[i], acc[i][j], 0, 0, 0);
        }
        __syncthreads();
    }

    // Epilogue: m = wm+i*16+l16, n = wn+j*16+quad*4+reg.
    #pragma unroll
    for (int i = 0; i < 4; ++i) {
        const int m = wm + i * 16 + l16;
        #pragma unroll
        for (int j = 0; j < 4; ++j) {
            const int nl = wn + j * 16 + quad * 4;
            const float4 b4 = *(const float4*)&bias[n0 + nl];
            float v0 = acc[i][j][0] + b4.x;
            float v1 = acc[i][j][1] + b4.y;
            float v2 = acc[i][j][2] + b4.z;
            float v3 = acc[i][j][3] + b4.w;
            v0 = 0.5f * v0 * (1.0f + erff(v0 * 0.70710678f));
            v1 = 0.5f * v1 * (1.0f + erff(v1 * 0.70710678f));
            v2 = 0.5f * v2 * (1.0f + erff(v2 * 0.70710678f));
            v3 = 0.5f * v3 * (1.0f + erff(v3 * 0.70710678f));
            uint2 p;
            p.x = pack_bf16x2(v0, v1);
            p.y = pack_bf16x2(v2, v3);
            *(uint2*)&Ct[m * CT_STRIDE + nl] = p;
        }
    }
    __syncthreads();

    #pragma unroll
    for (int it = 0; it < 8; ++it) {
        const int row = it * 16 + (tid >> 4);
        const int ch  = tid & 15;
        uint4 v = *(const uint4*)&Ct[row * CT_STRIDE + ch * 8];
        *(uint4*)&H[((size_t)(b * 256 + m0 + row)) * HID_ + n0 + ch * 8] = v;
    }
}

// ---------------------------------------------------------------------------
// fc2: out[b] = H[b] (256x1024 bf16) @ W2t[d]^T + b2, fp32 out.
// 64x64 tile, BK=128 (was 64): 8 barrier-pairs instead of 16; 16 MFMA +
// 16 ds_read_b128 per iter per wave. 16-chunk XOR swizzle (256 B rows).
__global__ __launch_bounds__(256) void fc2_gemm(
    const bf16_t* __restrict__ H,
    const bf16_t* __restrict__ W2t,   // D x 256 x 1024 [n][k]
    const float*  __restrict__ Bias,  // D x 256
    const int*    __restrict__ hetero,
    float*        __restrict__ Out)   // B x 256 x 256
{
    const int id   = blockIdx.x;          // 1024 blocks
    const int g    = id & 255;            // stride-256 ids share H-tile -> same XCD
    const int nidx = id >> 8;
    const int b    = g >> 2;
    const int m0   = (g & 3) * 64;
    const int n0   = nidx * 64;
    const int d    = hetero[2 * b];
    const bf16_t* W    = W2t + (size_t)d * OUT_ * HID_;
    const float*  bias = Bias + (size_t)d * OUT_;

    __shared__ __attribute__((aligned(16))) bf16_t LdsA[64 * 128];  // 16 KB
    __shared__ __attribute__((aligned(16))) bf16_t LdsB[64 * 128];  // 16 KB

    const int tid  = threadIdx.x;
    const int wave = tid >> 6;
    const int lane = tid & 63;
    const int l16  = lane & 15;
    const int quad = lane >> 4;
    const int wm   = (wave >> 1) * 32;
    const int wn   = (wave & 1) * 32;

    f32x4 acc[2][2] = {};

    for (int kk = 0; kk < HID_; kk += 128) {
        // A: 64 rows x 256 B; 4 calls/wave (4 rows x 16 chunks each).
        #pragma unroll
        for (int cc = 0; cc < 4; ++cc) {
            const int r0  = wave * 16 + cc * 4;
            const int row = r0 + (lane >> 4);
            const int cs  = (lane & 15) ^ (row & 15);
            gl_lds16(H + (size_t)(b * 256 + m0 + row) * HID_ + kk + cs * 8,
                     &LdsA[r0 * 128]);
        }
        // B: same shape from W2t rows.
        #pragma unroll
        for (int cc = 0; cc < 4; ++cc) {
            const int r0  = wave * 16 + cc * 4;
            const int row = r0 + (lane >> 4);
            const int cs  = (lane & 15) ^ (row & 15);
            gl_lds16(W + (size_t)(n0 + row) * HID_ + kk + cs * 8,
                     &LdsB[r0 * 128]);
        }
        __syncthreads();

        #pragma unroll
        for (int h = 0; h < 4; ++h) {
            bf16x8 af[2], bfg[2];
            #pragma unroll
            for (int i = 0; i < 2; ++i) {
                const int r = wm + i * 16 + l16;
                const int c = (h * 4 + quad) ^ (r & 15);
                af[i] = *(const bf16x8*)&LdsA[r * 128 + c * 8];
            }
            #pragma unroll
            for (int j = 0; j < 2; ++j) {
                const int r = wn + j * 16 + l16;
                const int c = (h * 4 + quad) ^ (r & 15);
                bfg[j] = *(const bf16x8*)&LdsB[r * 128 + c * 8];
            }
            #pragma unroll
            for (int i = 0; i < 2; ++i)
                #pragma unroll
                for (int j = 0; j < 2; ++j)   // swapped operands -> D^T
                    acc[i][j] = __builtin_amdgcn_mfma_f32_16x16x32_bf16(bfg[j], af[i], acc[i][j], 0, 0, 0);
        }
        __syncthreads();
    }

    // Store: m = m0+wm+i*16+l16; n = n0+wn+j*16+quad*4 (+reg). 16 B dwordx4/lane.
    #pragma unroll
    for (int i = 0; i < 2; ++i) {
        const int m = m0 + wm + i * 16 + l16;
        #pragma unroll
        for (int j = 0; j < 2; ++j) {
            const int nl = wn + j * 16 + quad * 4;
            const float4 b4 = *(const float4*)&bias[n0 + nl];
            float4 o;
            o.x = acc[i][j][0] + b4.x;
            o.y = acc[i][j][1] + b4.y;
            o.z = acc[i][j][2] + b4.z;
            o.w = acc[i][j][3] + b4.w;
            *(float4*)&Out[(size_t)(b * 256 + m) * OUT_ + n0 + nl] = o;
        }
    }
}

extern "C" void kernel_launch(void* const* d_in, const int* in_sizes, int n_in,
                              void* d_out, int out_size, void* d_ws, size_t ws_size,
                              hipStream_t stream) {
    const float* x         = (const float*)d_in[0];
    const int*   hetero    = (const int*)d_in[1];
    const float* fc1_table = (const float*)d_in[2];
    const float* fc2_table = (const float*)d_in[3];
    float*       out       = (float*)d_out;

    // Workspace layout (65,114,112 B — same budget validated in R6/R7/R10):
    char* ws = (char*)d_ws;
    bf16_t* W1t = (bf16_t*)(ws);                         // 20x1024x512 bf16 = 20,971,520
    bf16_t* W2t = (bf16_t*)(ws + 20971520);              // 20x256x1024 bf16 = 10,485,760
    float*  b1  = (float*)(ws + 31457280);               // 20x1024 fp32
    float*  b2  = (float*)(ws + 31539200);               // 20x256 fp32
    bf16_t* H   = (bf16_t*)(ws + 31559680);              // 64x256x1024 bf16 = 33,554,432

    // Xbf lives in d_out (16,777,216 B): fc1 reads it, fc2 overwrites later.
    bf16_t* Xbf = (bf16_t*)d_out;

    prepass<<<dim3(12032), 256, 0, stream>>>(
        x, Xbf, fc1_table, W1t, b1, fc2_table, W2t, b2);

    fc1_gemm<<<dim3(1024), 256, 0, stream>>>(Xbf, W1t, b1, hetero, H);
    fc2_gemm<<<dim3(1024), 256, 0, stream>>>(H, W2t, b2, hetero, out);
}